// Round 4
// baseline (3005.557 us; speedup 1.0000x reference)
//
#include <hip/hip_runtime.h>
#include <hip/hip_bf16.h>
#include <math.h>

// ------------------------------------------------------------------
// CRvNN forward on MI355X.
// Strategy: 16 independent batch elements -> 16 workgroups of 512
// threads; the whole 30-step recursion runs inside one kernel with all
// state in LDS (~148KB, opt-in). GEMMs via mfma_f32_16x16x32_bf16 with
// f32 accumulation; weights pre-transposed to bf16 [n][k] in d_ws.
// Exact early-exit when remaining <= 0.01 (step becomes identity).
// ------------------------------------------------------------------

typedef __bf16 bf16;
typedef bf16  bf16x8 __attribute__((ext_vector_type(8)));
typedef float f32x4  __attribute__((ext_vector_type(4)));

#define MFMA16(a,b,c) __builtin_amdgcn_mfma_f32_16x16x32_bf16((a),(b),(c),0,0,0)

constexpr int LDB = 264;  // bf16 row stride for 256-wide tiles (+16B pad: 2-way banks, free)
constexpr int LDI = 520;  // bf16 row stride for 512-wide inter
constexpr int LDP = 40;   // bf16 row stride for 32x32 prob mats

// LDS arena byte offsets
constexpr int OFF_SEQ   = 0;        // f32 [32][256]  32768
constexpr int OFF_SEQB  = 32768;    // bf16 [32][264] 16896
constexpr int OFF_L1    = 49664;    // bf16 [32][264] 16896
constexpr int OFF_R1    = 66560;    // bf16 [32][264] 16896  } sTrans f32[32][256] aliases
constexpr int OFF_TMP   = 83456;    // bf16 [32][264] 16896  } R1+TMP (dead by then)
constexpr int OFF_TRANS = 66560;    // f32 [32][256]  32768 (alias)
constexpr int OFF_INTER = 100352;   // bf16 [32][520] 33280
constexpr int OFF_LP    = 133632;   // f32 [32][32]   4096
constexpr int OFF_RP    = 137728;   // f32 [32][32]   4096
constexpr int OFF_LPB   = 141824;   // bf16 [32][40]  2560
constexpr int OFF_RPB   = 144384;   // bf16 [32][40]  2560
constexpr int OFF_ACT   = 146944;   // f32 [32]
constexpr int OFF_TP    = 147072;
constexpr int OFF_TS    = 147200;
constexpr int OFF_IM    = 147328;
constexpr int OFF_SELP  = 147456;
constexpr int OFF_LTM   = 147584;
constexpr int OFF_ENDM  = 147712;
constexpr int OFF_REM   = 147840;
constexpr int SMEM_BYTES = 147968;

__device__ __forceinline__ float gelu_f(float v) {
    return 0.5f * v * (1.0f + erff(v * 0.70710678118654752f));
}
__device__ __forceinline__ float sigm_f(float v) {
    return 1.0f / (1.0f + expf(-v));
}

// f32 [K][N] -> bf16 [N][K] transpose (32x32 tiles)
__global__ void transpose_bf16_kernel(const float* __restrict__ src,
                                      bf16* __restrict__ dst, int K, int N) {
    __shared__ float t[32][33];
    const int k0 = blockIdx.x * 32, n0 = blockIdx.y * 32;
    const int tx = threadIdx.x, ty = threadIdx.y;
#pragma unroll
    for (int i = 0; i < 4; ++i) {
        int k = k0 + ty + i * 8;
        t[ty + i * 8][tx] = src[(size_t)k * N + n0 + tx];
    }
    __syncthreads();
#pragma unroll
    for (int i = 0; i < 4; ++i) {
        int nn = n0 + ty + i * 8;
        dst[(size_t)nn * K + k0 + tx] = (bf16)t[tx][ty + i * 8];
    }
}

__global__ __launch_bounds__(512, 2)
void crvnn_main(const float* __restrict__ x, const float* __restrict__ inmask,
                const float* __restrict__ vSTART, const float* __restrict__ vEND,
                const float* __restrict__ b_init, const float* __restrict__ ln_g,
                const float* __restrict__ ln_b, const float* __restrict__ b_conv,
                const float* __restrict__ W_sc, const float* __restrict__ b_sc,
                const float* __restrict__ b_c1, const float* __restrict__ b_c2,
                const bf16* __restrict__ WbInit, const bf16* __restrict__ WbConv,
                const bf16* __restrict__ WbC1, const bf16* __restrict__ WbC2,
                float* __restrict__ out) {
    extern __shared__ char smem[];
    float* sSeq   = (float*)(smem + OFF_SEQ);
    bf16*  sSeqB  = (bf16*)(smem + OFF_SEQB);
    bf16*  sL1    = (bf16*)(smem + OFF_L1);
    bf16*  sR1    = (bf16*)(smem + OFF_R1);
    bf16*  sTmp   = (bf16*)(smem + OFF_TMP);
    float* sTrans = (float*)(smem + OFF_TRANS);
    bf16*  sInter = (bf16*)(smem + OFF_INTER);
    float* sLp    = (float*)(smem + OFF_LP);
    float* sRp    = (float*)(smem + OFF_RP);
    bf16*  sLpB   = (bf16*)(smem + OFF_LPB);
    bf16*  sRpB   = (bf16*)(smem + OFF_RPB);
    float* sAct   = (float*)(smem + OFF_ACT);
    float* sTp    = (float*)(smem + OFF_TP);
    float* sTs    = (float*)(smem + OFF_TS);
    float* sIm    = (float*)(smem + OFF_IM);
    float* sSelp  = (float*)(smem + OFF_SELP);
    float* sLtm   = (float*)(smem + OFF_LTM);
    float* sEndm  = (float*)(smem + OFF_ENDM);
    float* sRem   = (float*)(smem + OFF_REM);

    const int tid  = threadIdx.x;
    const int lane = tid & 63;
    const int w    = tid >> 6;   // wave id 0..7
    const int l15  = lane & 15;
    const int l4   = lane >> 4;  // 0..3
    const int rg   = tid >> 4;   // row-group row 0..31
    const int q    = tid & 15;   // lane within row group
    const int n    = blockIdx.x; // batch

    // ------------- masks / selp / active init -------------
    if (tid < 32) {
        const int r = tid;
        auto IM31 = [&](int j) -> float { return (j <= 0) ? 1.f : inmask[n * 30 + (j - 1)]; };
        float im_ye = (r == 0) ? 1.f : IM31(r - 1);
        float im_ne = (r <= 30) ? IM31(r) : 0.f;
        float endm  = im_ye - im_ne;
        float ins   = (r == 0) ? 0.f : im_ye;
        float ltm   = (r < 31) ? (IM31(r) - ((r <= 29) ? IM31(r + 1) : 0.f)) : 0.f;
        float selp  = ins * im_ne * (1.f - ltm);
        sIm[r] = im_ye; sEndm[r] = endm; sSelp[r] = selp; sLtm[r] = ltm; sAct[r] = im_ye;
    }
    __syncthreads();

    // ------------- build seq_pre (bf16) -------------
    {
        const int r = rg;
        const float em = sEndm[r];
#pragma unroll
        for (int k = 0; k < 16; ++k) {
            int c = q + 16 * k;
            float base = (r == 0) ? vSTART[c] : ((r <= 30) ? x[(size_t)(n * 30 + (r - 1)) * 256 + c] : 0.f);
            float v = em * vEND[c] + (1.f - em) * base;
            sSeqB[r * LDB + c] = (bf16)v;
        }
    }
    __syncthreads();

    // ------------- init GEMM: seq = LN(seq_pre @ W_init + b_init) * im -------------
    {
        f32x4 acc[2][2];
#pragma unroll
        for (int mt = 0; mt < 2; ++mt)
#pragma unroll
            for (int nt = 0; nt < 2; ++nt) acc[mt][nt] = f32x4{0.f, 0.f, 0.f, 0.f};
        for (int kt = 0; kt < 8; ++kt) {
            int kk = kt * 32 + l4 * 8;
            bf16x8 a0 = *(const bf16x8*)(sSeqB + l15 * LDB + kk);
            bf16x8 a1 = *(const bf16x8*)(sSeqB + (16 + l15) * LDB + kk);
#pragma unroll
            for (int nt = 0; nt < 2; ++nt) {
                bf16x8 b = *(const bf16x8*)(WbInit + (size_t)(32 * w + nt * 16 + l15) * 256 + kk);
                acc[0][nt] = MFMA16(a0, b, acc[0][nt]);
                acc[1][nt] = MFMA16(a1, b, acc[1][nt]);
            }
        }
#pragma unroll
        for (int mt = 0; mt < 2; ++mt)
#pragma unroll
            for (int nt = 0; nt < 2; ++nt)
#pragma unroll
                for (int i = 0; i < 4; ++i) {
                    int row = mt * 16 + l4 * 4 + i, col = 32 * w + nt * 16 + l15;
                    sSeq[row * 256 + col] = acc[mt][nt][i] + b_init[col];
                }
    }
    __syncthreads();
    {   // layernorm rows, * im
        const int r = rg;
        float s = 0.f, s2 = 0.f, vals[16];
#pragma unroll
        for (int k = 0; k < 16; ++k) {
            float v = sSeq[r * 256 + q + 16 * k];
            vals[k] = v; s += v; s2 += v * v;
        }
        for (int m = 1; m < 16; m <<= 1) { s += __shfl_xor(s, m); s2 += __shfl_xor(s2, m); }
        float mu = s * (1.f / 256.f);
        float var = s2 * (1.f / 256.f) - mu * mu;
        float rstd = rsqrtf(var + 1e-5f);
        float imr = sIm[r];
#pragma unroll
        for (int k = 0; k < 16; ++k) {
            int c = q + 16 * k;
            sSeq[r * 256 + c] = ((vals[k] - mu) * rstd * ln_g[c] + ln_b[c]) * imr;
        }
    }
    __syncthreads();

    // ==================== scan: 30 steps ====================
    for (int step = 0; step < 30; ++step) {
        // ---- phase 1: neighbor probs, remaining, refresh seqB, zero ts ----
        if (tid < 32) {
            const int i = tid;
            for (int j = 0; j < 32; ++j) {
                sRp[i * 32 + j] = 0.f; sLp[i * 32 + j] = 0.f;
                sRpB[i * LDP + j] = (bf16)0.f; sLpB[i * LDP + j] = (bf16)0.f;
            }
            float cc = 0.f;
            for (int j = i + 1; j < 32; ++j) {
                float am = sAct[j] * sIm[j];
                float cp = cc; cc += am;
                float v = (cc > 1.f) ? fmaxf(1.f - cp, 0.f) : am;
                v *= sIm[j];
                sRp[i * 32 + j] = v; sRpB[i * LDP + j] = (bf16)v;
            }
            cc = 0.f;
            for (int j = i - 1; j >= 0; --j) {
                float am = sAct[j] * sIm[j];
                float cp = cc; cc += am;
                float v = (cc > 1.f) ? fmaxf(1.f - cp, 0.f) : am;
                v *= sIm[j];
                sLp[i * 32 + j] = v; sLpB[i * LDP + j] = (bf16)v;
            }
            sTs[i] = 0.f;
            if (i == 0) {
                float rm = 0.f;
                for (int j = 0; j < 32; ++j) rm += sAct[j] * sSelp[j];
                *sRem = rm;
            }
        }
        {
            const int r = rg;
#pragma unroll
            for (int k = 0; k < 16; ++k) {
                int c = q + 16 * k;
                sSeqB[r * LDB + c] = (bf16)sSeq[r * 256 + c];
            }
        }
        __syncthreads();
        if (*sRem <= 0.01f) break;  // u == 0 -> all remaining steps are identity (exact)

        // ---- phase 2: L1 = Lp@seq, R1 = Rp@seq ----
        {
            bf16x8 aL0 = *(const bf16x8*)(sLpB + l15 * LDP + l4 * 8);
            bf16x8 aL1v = *(const bf16x8*)(sLpB + (16 + l15) * LDP + l4 * 8);
            bf16x8 aR0 = *(const bf16x8*)(sRpB + l15 * LDP + l4 * 8);
            bf16x8 aR1v = *(const bf16x8*)(sRpB + (16 + l15) * LDP + l4 * 8);
            f32x4 accL[2][2], accR[2][2];
#pragma unroll
            for (int mt = 0; mt < 2; ++mt)
#pragma unroll
                for (int nt = 0; nt < 2; ++nt) { accL[mt][nt] = f32x4{0.f,0.f,0.f,0.f}; accR[mt][nt] = f32x4{0.f,0.f,0.f,0.f}; }
#pragma unroll
            for (int nt = 0; nt < 2; ++nt) {
                int n0 = 32 * w + nt * 16;
                bf16x8 bx;
#pragma unroll
                for (int s2 = 0; s2 < 8; ++s2) bx[s2] = sSeqB[(l4 * 8 + s2) * LDB + n0 + l15];
                accL[0][nt] = MFMA16(aL0, bx, accL[0][nt]);
                accL[1][nt] = MFMA16(aL1v, bx, accL[1][nt]);
                accR[0][nt] = MFMA16(aR0, bx, accR[0][nt]);
                accR[1][nt] = MFMA16(aR1v, bx, accR[1][nt]);
            }
#pragma unroll
            for (int mt = 0; mt < 2; ++mt)
#pragma unroll
                for (int nt = 0; nt < 2; ++nt)
#pragma unroll
                    for (int i = 0; i < 4; ++i) {
                        int row = mt * 16 + l4 * 4 + i, col = 32 * w + nt * 16 + l15;
                        sL1[row * LDB + col] = (bf16)accL[mt][nt][i];
                        sR1[row * LDB + col] = (bf16)accR[mt][nt][i];
                    }
        }
        __syncthreads();

        // ---- phase 3: L2 = Lp@L1 -> sTmp ; inter = gelu([L1,seq] @ W_c1 + b_c1) ----
        {
            bf16x8 aL0 = *(const bf16x8*)(sLpB + l15 * LDP + l4 * 8);
            bf16x8 aL1v = *(const bf16x8*)(sLpB + (16 + l15) * LDP + l4 * 8);
            f32x4 acc2[2][2];
#pragma unroll
            for (int mt = 0; mt < 2; ++mt)
#pragma unroll
                for (int nt = 0; nt < 2; ++nt) acc2[mt][nt] = f32x4{0.f,0.f,0.f,0.f};
#pragma unroll
            for (int nt = 0; nt < 2; ++nt) {
                int n0 = 32 * w + nt * 16;
                bf16x8 bx;
#pragma unroll
                for (int s2 = 0; s2 < 8; ++s2) bx[s2] = sL1[(l4 * 8 + s2) * LDB + n0 + l15];
                acc2[0][nt] = MFMA16(aL0, bx, acc2[0][nt]);
                acc2[1][nt] = MFMA16(aL1v, bx, acc2[1][nt]);
            }
#pragma unroll
            for (int mt = 0; mt < 2; ++mt)
#pragma unroll
                for (int nt = 0; nt < 2; ++nt)
#pragma unroll
                    for (int i = 0; i < 4; ++i) {
                        int row = mt * 16 + l4 * 4 + i, col = 32 * w + nt * 16 + l15;
                        sTmp[row * LDB + col] = (bf16)acc2[mt][nt][i];
                    }
            // c1 GEMM
            f32x4 c1a[2][4];
#pragma unroll
            for (int mt = 0; mt < 2; ++mt)
#pragma unroll
                for (int nt = 0; nt < 4; ++nt) c1a[mt][nt] = f32x4{0.f,0.f,0.f,0.f};
            for (int kt = 0; kt < 16; ++kt) {
                const bf16* Ab = (kt < 8) ? sL1 : sSeqB;
                int kk = (kt & 7) * 32 + l4 * 8;
                bf16x8 a0 = *(const bf16x8*)(Ab + l15 * LDB + kk);
                bf16x8 a1 = *(const bf16x8*)(Ab + (16 + l15) * LDB + kk);
#pragma unroll
                for (int nt = 0; nt < 4; ++nt) {
                    bf16x8 b = *(const bf16x8*)(WbC1 + (size_t)(64 * w + nt * 16 + l15) * 512 + kt * 32 + l4 * 8);
                    c1a[0][nt] = MFMA16(a0, b, c1a[0][nt]);
                    c1a[1][nt] = MFMA16(a1, b, c1a[1][nt]);
                }
            }
#pragma unroll
            for (int mt = 0; mt < 2; ++mt)
#pragma unroll
                for (int nt = 0; nt < 4; ++nt)
#pragma unroll
                    for (int i = 0; i < 4; ++i) {
                        int row = mt * 16 + l4 * 4 + i, col = 64 * w + nt * 16 + l15;
                        float v = c1a[mt][nt][i] + b_c1[col];
                        sInter[row * LDI + col] = (bf16)gelu_f(v);
                    }
        }
        __syncthreads();

        // ---- phase 4: conv slices 0..3 (L2, L1, seq, R1) ----
        f32x4 cva[2][2];
#pragma unroll
        for (int mt = 0; mt < 2; ++mt)
#pragma unroll
            for (int nt = 0; nt < 2; ++nt) cva[mt][nt] = f32x4{0.f,0.f,0.f,0.f};
        {
            const bf16* slices[4] = { sTmp, sL1, sSeqB, sR1 };
#pragma unroll
            for (int sl = 0; sl < 4; ++sl) {
                const bf16* Ab = slices[sl];
                for (int kt = 0; kt < 8; ++kt) {
                    int kk = kt * 32 + l4 * 8;
                    bf16x8 a0 = *(const bf16x8*)(Ab + l15 * LDB + kk);
                    bf16x8 a1 = *(const bf16x8*)(Ab + (16 + l15) * LDB + kk);
#pragma unroll
                    for (int nt = 0; nt < 2; ++nt) {
                        bf16x8 b = *(const bf16x8*)(WbConv + (size_t)(32 * w + nt * 16 + l15) * 1280 + sl * 256 + kt * 32 + l4 * 8);
                        cva[0][nt] = MFMA16(a0, b, cva[0][nt]);
                        cva[1][nt] = MFMA16(a1, b, cva[1][nt]);
                    }
                }
            }
        }
        __syncthreads();

        // ---- phase 5: R2 = Rp@R1 -> sTmp ----
        {
            bf16x8 aR0 = *(const bf16x8*)(sRpB + l15 * LDP + l4 * 8);
            bf16x8 aR1v = *(const bf16x8*)(sRpB + (16 + l15) * LDP + l4 * 8);
            f32x4 acc2[2][2];
#pragma unroll
            for (int mt = 0; mt < 2; ++mt)
#pragma unroll
                for (int nt = 0; nt < 2; ++nt) acc2[mt][nt] = f32x4{0.f,0.f,0.f,0.f};
#pragma unroll
            for (int nt = 0; nt < 2; ++nt) {
                int n0 = 32 * w + nt * 16;
                bf16x8 bx;
#pragma unroll
                for (int s2 = 0; s2 < 8; ++s2) bx[s2] = sR1[(l4 * 8 + s2) * LDB + n0 + l15];
                acc2[0][nt] = MFMA16(aR0, bx, acc2[0][nt]);
                acc2[1][nt] = MFMA16(aR1v, bx, acc2[1][nt]);
            }
#pragma unroll
            for (int mt = 0; mt < 2; ++mt)
#pragma unroll
                for (int nt = 0; nt < 2; ++nt)
#pragma unroll
                    for (int i = 0; i < 4; ++i) {
                        int row = mt * 16 + l4 * 4 + i, col = 32 * w + nt * 16 + l15;
                        sTmp[row * LDB + col] = (bf16)acc2[mt][nt][i];
                    }
        }
        __syncthreads();

        // ---- phase 6: conv slice 4 (R2) + ts = gelu(h) @ W_sc ----
        {
            for (int kt = 0; kt < 8; ++kt) {
                int kk = kt * 32 + l4 * 8;
                bf16x8 a0 = *(const bf16x8*)(sTmp + l15 * LDB + kk);
                bf16x8 a1 = *(const bf16x8*)(sTmp + (16 + l15) * LDB + kk);
#pragma unroll
                for (int nt = 0; nt < 2; ++nt) {
                    bf16x8 b = *(const bf16x8*)(WbConv + (size_t)(32 * w + nt * 16 + l15) * 1280 + 1024 + kt * 32 + l4 * 8);
                    cva[0][nt] = MFMA16(a0, b, cva[0][nt]);
                    cva[1][nt] = MFMA16(a1, b, cva[1][nt]);
                }
            }
#pragma unroll
            for (int mt = 0; mt < 2; ++mt)
#pragma unroll
                for (int i = 0; i < 4; ++i) {
                    int row = mt * 16 + l4 * 4 + i;
                    float p = 0.f;
#pragma unroll
                    for (int nt = 0; nt < 2; ++nt) {
                        int col = 32 * w + nt * 16 + l15;
                        float hv = gelu_f(cva[mt][nt][i] + b_conv[col]);
                        p += hv * W_sc[col];
                    }
                    p += __shfl_xor(p, 1); p += __shfl_xor(p, 2);
                    p += __shfl_xor(p, 4); p += __shfl_xor(p, 8);
                    if (l15 == 0) atomicAdd(&sTs[row], p);
                }
        }
        __syncthreads();

        // ---- phase 7: tp ; c2 GEMM ; gates -> trans_pre ----
        if (tid < 32) {
            float t = sTs[tid] + b_sc[0];
            sTp[tid] = sSelp[tid] * sigm_f(t);
        }
        {
            f32x4 c2a[2][2][4];
#pragma unroll
            for (int mt = 0; mt < 2; ++mt)
#pragma unroll
                for (int di = 0; di < 2; ++di)
#pragma unroll
                    for (int g = 0; g < 4; ++g) c2a[mt][di][g] = f32x4{0.f,0.f,0.f,0.f};
            for (int kt = 0; kt < 16; ++kt) {
                int kk = kt * 32 + l4 * 8;
                bf16x8 a0 = *(const bf16x8*)(sInter + l15 * LDI + kk);
                bf16x8 a1 = *(const bf16x8*)(sInter + (16 + l15) * LDI + kk);
#pragma unroll
                for (int di = 0; di < 2; ++di)
#pragma unroll
                    for (int g = 0; g < 4; ++g) {
                        int col = g * 256 + (2 * w + di) * 16 + l15;
                        bf16x8 b = *(const bf16x8*)(WbC2 + (size_t)col * 512 + kk);
                        c2a[0][di][g] = MFMA16(a0, b, c2a[0][di][g]);
                        c2a[1][di][g] = MFMA16(a1, b, c2a[1][di][g]);
                    }
            }
#pragma unroll
            for (int mt = 0; mt < 2; ++mt)
#pragma unroll
                for (int di = 0; di < 2; ++di)
#pragma unroll
                    for (int i = 0; i < 4; ++i) {
                        int row = mt * 16 + l4 * 4 + i;
                        int d = (2 * w + di) * 16 + l15;
                        float c0 = c2a[mt][di][0][i] + b_c2[d];
                        float c1v = c2a[mt][di][1][i] + b_c2[256 + d];
                        float c2v = c2a[mt][di][2][i] + b_c2[512 + d];
                        float c3v = c2a[mt][di][3][i] + b_c2[768 + d];
                        float g0 = sigm_f(c0), g1 = sigm_f(c1v), g2 = sigm_f(c2v);
                        float lc = (float)sL1[row * LDB + d];
                        float sv = sSeq[row * 256 + d];
                        sTrans[row * 256 + d] = g0 * lc + g1 * sv + g2 * c3v;
                    }
        }
        __syncthreads();

        // ---- phase 8: trans = LN(trans_pre); seq update; active update ----
        {
            const int r = rg;
            float s = 0.f, s2 = 0.f, vals[16];
#pragma unroll
            for (int k = 0; k < 16; ++k) {
                float v = sTrans[r * 256 + q + 16 * k];
                vals[k] = v; s += v; s2 += v * v;
            }
            for (int m = 1; m < 16; m <<= 1) { s += __shfl_xor(s, m); s2 += __shfl_xor(s2, m); }
            float mu = s * (1.f / 256.f);
            float var = s2 * (1.f / 256.f) - mu * mu;
            float rstd = rsqrtf(var + 1e-5f);
            float tpv = sTp[r], imr = sIm[r];
#pragma unroll
            for (int k = 0; k < 16; ++k) {
                int c = q + 16 * k;
                float tr = (vals[k] - mu) * rstd * ln_g[c] + ln_b[c];
                float sv = sSeq[r * 256 + c];
                sSeq[r * 256 + c] = (tpv * tr + (1.f - tpv) * sv) * imr;
            }
        }
        if (tid < 32) {
            const int j = tid;
            float cons = 0.f;
            for (int i = 0; i < 32; ++i) cons += sLp[i * 32 + j] * sTp[i];
            sAct[j] = fmaxf(sAct[j] - cons, 0.f);
        }
        __syncthreads();
    }

    // ---- output: sum_j ltm[j] * seq[j] ----
    if (tid < 256) {
        float o = 0.f;
        for (int j = 0; j < 32; ++j) o += sLtm[j] * sSeq[j * 256 + tid];
        out[(size_t)n * 256 + tid] = o;
    }
}

extern "C" void kernel_launch(void* const* d_in, const int* in_sizes, int n_in,
                              void* d_out, int out_size, void* d_ws, size_t ws_size,
                              hipStream_t stream) {
    const float* x       = (const float*)d_in[0];
    const float* inmask  = (const float*)d_in[1];
    const float* vSTART  = (const float*)d_in[2];
    const float* vEND    = (const float*)d_in[3];
    const float* W_init  = (const float*)d_in[4];
    const float* b_init  = (const float*)d_in[5];
    const float* ln_g    = (const float*)d_in[6];
    const float* ln_b    = (const float*)d_in[7];
    const float* W_conv  = (const float*)d_in[8];
    const float* b_conv  = (const float*)d_in[9];
    const float* W_sc    = (const float*)d_in[10];
    const float* b_sc    = (const float*)d_in[11];
    const float* W_c1    = (const float*)d_in[12];
    const float* b_c1    = (const float*)d_in[13];
    const float* W_c2    = (const float*)d_in[14];
    const float* b_c2    = (const float*)d_in[15];
    float* out = (float*)d_out;

    bf16* WbInit = (bf16*)d_ws;                 // 256 x 256
    bf16* WbConv = WbInit + 256 * 256;          // 256 x 1280
    bf16* WbC1   = WbConv + 256 * 1280;         // 512 x 512
    bf16* WbC2   = WbC1 + 512 * 512;            // 1024 x 512

    dim3 tb(32, 8);
    transpose_bf16_kernel<<<dim3(256 / 32, 256 / 32), tb, 0, stream>>>(W_init, WbInit, 256, 256);
    transpose_bf16_kernel<<<dim3(1280 / 32, 256 / 32), tb, 0, stream>>>(W_conv, WbConv, 1280, 256);
    transpose_bf16_kernel<<<dim3(512 / 32, 512 / 32), tb, 0, stream>>>(W_c1, WbC1, 512, 512);
    transpose_bf16_kernel<<<dim3(512 / 32, 1024 / 32), tb, 0, stream>>>(W_c2, WbC2, 512, 1024);

    hipFuncSetAttribute((const void*)crvnn_main,
                        hipFuncAttributeMaxDynamicSharedMemorySize, SMEM_BYTES);
    crvnn_main<<<dim3(16), dim3(512), SMEM_BYTES, stream>>>(
        x, inmask, vSTART, vEND, b_init, ln_g, ln_b, b_conv, W_sc, b_sc,
        b_c1, b_c2, WbInit, WbConv, WbC1, WbC2, out);
}